// Round 6
// baseline (212.618 us; speedup 1.0000x reference)
//
#include <hip/hip_runtime.h>
#include <hip/hip_bf16.h>

#define EPSW 1e-6f
#define BASEP 0xAAAAAAAAu   // harness ws poison pattern (deterministic)

typedef __attribute__((ext_vector_type(4))) float floatx4;
typedef __attribute__((ext_vector_type(8))) short shortx8;   // 8 bf16 (4 VGPRs)

// round-to-nearest-even float -> bf16 bits (finite inputs)
__device__ __forceinline__ unsigned short f2bf(float f) {
    unsigned int u = __float_as_uint(f);
    u = (u + 0x7fffu + ((u >> 16) & 1u)) >> 16;
    return (unsigned short)u;
}

// bounded spin: accepts zero-init (tgt) or 0xAA-poison-init (tgt+BASEP) counter
// bases. Counters are monotonic and stop exactly at target, so equality is
// always eventually observed. Bound => pathological case degrades to visible
// absmax failure instead of a hang.
__device__ __forceinline__ void spin_until(const unsigned int* p, unsigned int tgt) {
    for (int i = 0; i < 1000000; ++i) {
        const unsigned int v =
            __hip_atomic_load(p, __ATOMIC_RELAXED, __HIP_MEMORY_SCOPE_AGENT);
        if (v == tgt || v == tgt + BASEP) return;
        __builtin_amdgcn_s_sleep(2);
    }
}

// ---------------------------------------------------------------------------
// One dispatch: 256 blocks x 512 threads (8 waves; LDS 50688 B -> >=2
// blocks/CU possible, grid 256 = 1/CU).
// Produce:  all blocks: xt tile (64 rows x 32 kg transpose, bf16 A-frag
//           layout [kg][row][8], K padded to 2048) -> arrive ctr[bid>>3].
//           blocks 0..15: wt slice (16 kg cols x 128 h, B-frag layout)
//           -> arrive ctr[32].
//           blocks 240..255: full A in LDS (redundant, cheap) + 4-col slice
//           of Mt=(A@A)^T -> arrive ctr[33].
// Consume:  block (b=bid>>3, ht=bid&7): wait ctr[b]==8 && ctr[32]==16,
//           acquire-fence, MFMA z-tile[64n x 16h] over K (8 waves = 4 row-
//           tiles x 2 K-halves), wait ctr[33]==16 (hidden behind MFMA),
//           reduce K-halves in LDS, apply M + bias, store y.
// Deadlock-free: every block produces before any spin; producers never spin
// first; bounded spins. Cross-XCD visibility: __threadfence (agent release/
// acquire => buffer_wbl2 / buffer_inv on gfx950) around device-scope atomics.
// ---------------------------------------------------------------------------
__global__ __launch_bounds__(512, 2) void fused(
        const float* __restrict__ x, const float* __restrict__ W,
        const int* __restrict__ ei, const float* __restrict__ ew,
        const float* __restrict__ bias,
        unsigned short* __restrict__ xt, unsigned short* __restrict__ wt,
        float* __restrict__ Mt, unsigned int* __restrict__ ctr,
        float* __restrict__ y) {
    __shared__ __align__(16) unsigned char smem[50688];
    const int bid = blockIdx.x;
    const int t   = threadIdx.x;

    // ===== produce: xt tile =====
    {
        unsigned short(*tile)[264] = (unsigned short(*)[264])smem;  // +8 pad
        const int rb   = (bid >> 3) * 64;      // 32 row-tiles
        const int kgb  = (bid & 7) * 32;       // 8 kg-tiles
        const int kbas = kgb * 8;
#pragma unroll
        for (int i = 0; i < 8; ++i) {
            const int idx = i * 512 + t;
            const int r   = idx >> 6;          // 0..63
            const int kc  = (idx & 63) * 4;    // 0..252
            const int k   = kbas + kc;
            floatx4 v = (floatx4){0.f, 0.f, 0.f, 0.f};
            if (k < 2000)
                v = *(const floatx4*)(x + (size_t)(rb + r) * 2000 + k);
            tile[r][kc + 0] = f2bf(v.x);
            tile[r][kc + 1] = f2bf(v.y);
            tile[r][kc + 2] = f2bf(v.z);
            tile[r][kc + 3] = f2bf(v.w);
        }
        __syncthreads();
#pragma unroll
        for (int i = 0; i < 4; ++i) {
            const int kg_l = i * 8 + (t >> 6);  // wave-uniform, 0..31
            const int r    = t & 63;
            const shortx8 g = *(const shortx8*)&tile[r][kg_l * 8];
            *(shortx8*)(xt + ((size_t)(kgb + kg_l) * 2048 + rb + r) * 8) = g;
        }
    }

    // ===== produce: wt slice (blocks 0..15) =====
    if (bid < 16) {
#pragma unroll
        for (int i = 0; i < 4; ++i) {
            const int G  = i * 512 + t;              // 0..2047
            const int kg = bid * 16 + (G >> 7);      // 16 kg cols per block
            const int h  = G & 127;
            const int k  = kg * 8;
            floatx4 v0 = (floatx4){0.f, 0.f, 0.f, 0.f};
            floatx4 v1 = (floatx4){0.f, 0.f, 0.f, 0.f};
            if (k < 2000) {  // kg<=249 -> whole granule valid
                v0 = *(const floatx4*)(W + (size_t)h * 2000 + k);
                v1 = *(const floatx4*)(W + (size_t)h * 2000 + k + 4);
            }
            unsigned short* p = wt + ((size_t)kg * 128 + h) * 8;
            p[0] = f2bf(v0.x); p[1] = f2bf(v0.y); p[2] = f2bf(v0.z); p[3] = f2bf(v0.w);
            p[4] = f2bf(v1.x); p[5] = f2bf(v1.y); p[6] = f2bf(v1.z); p[7] = f2bf(v1.w);
        }
    }

    // arrivals for xt + wt (release)
    __syncthreads();          // all waves' stores drained (vmcnt before barrier)
    __threadfence();          // agent release: L2 writeback
    if (t == 0) {
        atomicAdd(&ctr[bid >> 3], 1u);
        if (bid < 16) atomicAdd(&ctr[32], 1u);
    }

    // ===== produce: A + Mt slice (blocks 240..255) =====
    if (bid >= 240) {
        float* A    = (float*)(smem + 33792);   // 16384 B (disjoint from tile)
        float* deg  = (float*)(smem + 50176);   // 256 B
        float* dinv = (float*)(smem + 50432);   // 256 B
        if (t < 64) deg[t] = 1.0f;              // self-loop pre-added
        for (int i = t; i < 4096; i += 512) A[i] = 0.0f;
        __syncthreads();
        const int* srcp = ei;
        const int* dstp = ei + 4096;
        for (int e = t; e < 4096; e += 512) {
            float w = ew[e];
            w = (w <= 0.0f) ? EPSW : w;
            atomicAdd(&deg[dstp[e]], w);
        }
        __syncthreads();
        if (t < 64) dinv[t] = 1.0f / sqrtf(deg[t]);
        __syncthreads();
        for (int e = t; e < 4096; e += 512) {
            float w = ew[e];
            w = (w <= 0.0f) ? EPSW : w;
            const int s = srcp[e], d = dstp[e];
            atomicAdd(&A[d * 64 + s], dinv[s] * w * dinv[d]);
        }
        if (t < 64) atomicAdd(&A[t * 64 + t], dinv[t] * dinv[t]);
        __syncthreads();
        if (t < 256) {                          // Mt[c][n] = (A@A)[n][c], 4 cols
            const int c = (bid - 240) * 4 + (t >> 6);
            const int n = t & 63;
            float s = 0.0f;
#pragma unroll 8
            for (int k = 0; k < 64; ++k) s += A[n * 64 + k] * A[k * 64 + c];
            Mt[c * 64 + n] = s;
        }
        __syncthreads();
        __threadfence();
        if (t == 0) atomicAdd(&ctr[33], 1u);
    }

    // ===== consume: wait xt(b) + wt =====
    const int b  = bid >> 3;
    const int ht = bid & 7;
    if (t == 0) {
        spin_until(&ctr[b], 8u);
        spin_until(&ctr[32], 16u);
    }
    __syncthreads();
    __threadfence();          // acquire: invalidate stale L1

    // ===== gemm: z-tile[64 rows][16 h] for batch b, K split across 2 wave-halves
    const int wave = t >> 6, lane = t & 63;
    const int m = lane & 15, q = lane >> 4;
    const int rt = wave & 3, kh = wave >> 2;

    const shortx8* Ag = (const shortx8*)xt;
    const shortx8* Bg = (const shortx8*)wt;
    int ga = (kh * 128 + q) * 2048 + b * 64 + rt * 16 + m;  // +8192 per kt
    int gb = (kh * 128 + q) * 128 + ht * 16 + m;            // +512 per kt

    floatx4 acc0 = (floatx4){0.f, 0.f, 0.f, 0.f};
    floatx4 acc1 = (floatx4){0.f, 0.f, 0.f, 0.f};
#pragma unroll 4
    for (int kt = 0; kt < 32; kt += 2) {
        const shortx8 a0 = Ag[ga];
        const shortx8 b0 = Bg[gb];
        const shortx8 a1 = Ag[ga + 8192];
        const shortx8 b1 = Bg[gb + 512];
        acc0 = __builtin_amdgcn_mfma_f32_16x16x32_bf16(a0, b0, acc0, 0, 0, 0);
        acc1 = __builtin_amdgcn_mfma_f32_16x16x32_bf16(a1, b1, acc1, 0, 0, 0);
        ga += 16384; gb += 1024;
    }
    acc0 += acc1;

    // ===== wait Mt (hidden behind the MFMA work above) =====
    if (t == 0) spin_until(&ctr[33], 16u);
    __syncthreads();
    __threadfence();

    // ===== reduce K-halves + apply M + bias =====
    float* Ms      = (float*)smem;                 // 16384 B
    float(*zs)[17] = (float(*)[17])(smem + 16384); // 4624 B
    {   // stage Ms
        const floatx4* Mg4 = (const floatx4*)Mt;
        floatx4* Ms4 = (floatx4*)Ms;
        Ms4[t]       = Mg4[t];
        Ms4[t + 512] = Mg4[t + 512];
    }
    // C/D layout: row = q*4+v, col = m.  zs padded [64][17]: conflict-free.
    if (kh == 0) {
#pragma unroll
        for (int v = 0; v < 4; ++v) zs[rt * 16 + q * 4 + v][m] = acc0[v];
    }
    __syncthreads();
    if (kh == 1) {
#pragma unroll
        for (int v = 0; v < 4; ++v) zs[rt * 16 + q * 4 + v][m] += acc0[v];
    }
    __syncthreads();
    {
        const int n0 = t >> 4;        // 0..31
        const int h  = t & 15;
        const float bv = bias[ht * 16 + h];
        float s0 = bv, s1 = bv;
#pragma unroll
        for (int mm = 0; mm < 64; ++mm) {
            const float zv = zs[mm][h];                 // 16-lane broadcast
            s0 += Ms[mm * 64 + n0]      * zv;           // 4 banks x broadcast
            s1 += Ms[mm * 64 + n0 + 32] * zv;
        }
        float* yp = y + (size_t)b * 8192 + ht * 16 + h;
        yp[(size_t)n0 * 128]        = s0;
        yp[(size_t)(n0 + 32) * 128] = s1;
    }
}

extern "C" void kernel_launch(void* const* d_in, const int* in_sizes, int n_in,
                              void* d_out, int out_size, void* d_ws, size_t ws_size,
                              hipStream_t stream) {
    const float* x    = (const float*)d_in[0];   // (2048, 2000) fp32
    const int*   ei   = (const int*)d_in[1];     // (2, 4096)
    const float* ew   = (const float*)d_in[2];   // (4096,)
    const float* W    = (const float*)d_in[3];   // (128, 2000) fp32
    const float* bias = (const float*)d_in[4];   // (128,)
    float* y = (float*)d_out;                    // (32, 64, 128) fp32

    float* Mt = (float*)d_ws;                            // 4096 f
    unsigned short* xt = (unsigned short*)(Mt + 4096);   // 256*2048*8 bf16 (8 MB)
    unsigned short* wt = xt + 4194304;                   // 256*128*8 bf16 (512 KB)
    unsigned int* ctr  = (unsigned int*)(wt + 262144);   // [0..31]=xt/b, 32=wt, 33=Mt

    fused<<<256, 512, 0, stream>>>(x, W, ei, ew, bias, xt, wt, Mt, ctr, y);
}

// Round 7
// 102.495 us; speedup vs baseline: 2.0744x; 2.0744x over previous
//
#include <hip/hip_runtime.h>
#include <hip/hip_bf16.h>

#define EPSW 1e-6f

typedef __attribute__((ext_vector_type(4))) float floatx4;
typedef __attribute__((ext_vector_type(8))) short shortx8;   // 8 bf16 (4 VGPRs)

// pack 8 fp32 -> 8 bf16 (round-half-up: +0x8000, take hi16 via v_perm).
// <=0.5 ulp vs RNE; validated absmax-equal in rounds 3/5.
__device__ __forceinline__ shortx8 pack8(floatx4 a, floatx4 b) {
    union { shortx8 v; unsigned int u[4]; } r;
    const unsigned a0 = __float_as_uint(a.x) + 0x8000u, a1 = __float_as_uint(a.y) + 0x8000u;
    const unsigned a2 = __float_as_uint(a.z) + 0x8000u, a3 = __float_as_uint(a.w) + 0x8000u;
    const unsigned b0 = __float_as_uint(b.x) + 0x8000u, b1 = __float_as_uint(b.y) + 0x8000u;
    const unsigned b2 = __float_as_uint(b.z) + 0x8000u, b3 = __float_as_uint(b.w) + 0x8000u;
    r.u[0] = __builtin_amdgcn_perm(a1, a0, 0x07060302u);
    r.u[1] = __builtin_amdgcn_perm(a3, a2, 0x07060302u);
    r.u[2] = __builtin_amdgcn_perm(b1, b0, 0x07060302u);
    r.u[3] = __builtin_amdgcn_perm(b3, b2, 0x07060302u);
    return r.v;
}

// ---------------------------------------------------------------------------
// ONE dispatch, zero cross-block deps. 256 blocks x 512 threads.
// Block bid = ht*32 + b  (b = batch 0..31, ht = h-tile 0..7). XCD round-robin
// (bid%8 == b%8) pins 4 batches per XCD -> x re-reads (8x per row) hit that
// XCD's L2 (2 MB x-slices + 1 MB W << 4 MB L2).
// Prologue: every block redundantly builds A (normalized adjacency, LDS
//   atomics) and Ms[c*64+n] = (A@A)[n][c]  (~512 MAC/thread, <1 us).
// Main: z-tile[64 rows x 16 h] over K=2000 (pad 2048), double-buffered LDS
//   staging straight from fp32 x/W with inline bf16 pack; 8 waves =
//   (rt 0..3) x (kh 0..1), 2 MFMA/wave per 128-K chunk, 16 chunks.
// Epilogue: kh-halves reduced via LDS (zs[64][17]), y = M.z + bias
//   (round-5-validated pattern).
// LDS 59904 B: xs 2x17408 | ww 2x4352 | Ms 16384; A/deg/zs overlay xs.
// ---------------------------------------------------------------------------
#define XSTR 136   // 128 + 8 pad, bf16 units; row stride 272 B (4-bank skew)

__global__ __launch_bounds__(512, 2) void fused_all(
        const float* __restrict__ x, const float* __restrict__ W,
        const int* __restrict__ ei, const float* __restrict__ ew,
        const float* __restrict__ bias, float* __restrict__ y) {
    __shared__ __align__(16) unsigned short smem[29952];
    unsigned short* xs0 = smem;                 // 8704 shorts
    unsigned short* xs1 = smem + 8704;
    unsigned short* ww0 = smem + 17408;         // 2176 shorts
    unsigned short* ww1 = smem + 19584;
    float* Ms = (float*)(smem + 21760);         // 4096 f
    float* A    = (float*)smem;                 // overlay xs0 (prologue)
    float* deg  = (float*)xs1;                  // overlay xs1 (prologue)
    float* dinv = deg + 64;
    float(*zs)[17] = (float(*)[17])smem;        // overlay xs0 (epilogue)

    const int t   = threadIdx.x;
    const int bid = blockIdx.x;
    const int b   = bid & 31;
    const int ht  = bid >> 5;

    // ================= prologue: A + Ms (redundant per block) =================
    {
        if (t < 64) deg[t] = 1.0f;              // self-loop pre-added
        for (int i = t; i < 4096; i += 512) A[i] = 0.0f;
        __syncthreads();
        const int* srcp = ei;
        const int* dstp = ei + 4096;
#pragma unroll
        for (int i = 0; i < 8; ++i) {
            const int e = i * 512 + t;
            float w = ew[e];
            w = (w <= 0.0f) ? EPSW : w;
            atomicAdd(&deg[dstp[e]], w);
        }
        __syncthreads();
        if (t < 64) dinv[t] = 1.0f / sqrtf(deg[t]);
        __syncthreads();
#pragma unroll
        for (int i = 0; i < 8; ++i) {
            const int e = i * 512 + t;
            float w = ew[e];
            w = (w <= 0.0f) ? EPSW : w;
            const int s = srcp[e], d = dstp[e];
            atomicAdd(&A[d * 64 + s], dinv[s] * w * dinv[d]);
        }
        if (t < 64) atomicAdd(&A[t * 64 + t], dinv[t] * dinv[t]);
        __syncthreads();
        // Ms[c*64+n] = (A@A)[n][c]
#pragma unroll
        for (int i = 0; i < 8; ++i) {
            const int idx = i * 512 + t;
            const int n = idx >> 6, c = idx & 63;
            float s = 0.0f;
#pragma unroll 8
            for (int k = 0; k < 64; ++k) s += A[n * 64 + k] * A[k * 64 + c];
            Ms[c * 64 + n] = s;
        }
        __syncthreads();   // A/deg regions free
    }

    // ================= main: GEMM over K, double-buffered =================
    const int wave = t >> 6, lane = t & 63;
    const int m = lane & 15, q = lane >> 4;
    const int rt = wave & 3, kh = wave >> 2;

    const float* xb = x + (size_t)b * 64 * 2000;
    const float* Wb = W + (size_t)ht * 16 * 2000;

    // staging coords: x = 1024 granules-of-8 (2/thread), W = 256 (t<256)
    const int xr0 = t >> 4,         xk0 = (t & 15) * 8;         // g = t
    const int xr1 = (t + 512) >> 4, xk1 = xk0;                  // g = t+512
    const int wr  = t >> 4,         wk  = (t & 15) * 8;         // t<256

    floatx4 px0a, px0b, px1a, px1b, pwa, pwb;
    const floatx4 zero4 = (floatx4){0.f, 0.f, 0.f, 0.f};

#define LOAD_CHUNK(kbase)                                                     \
    {                                                                         \
        const int k0 = (kbase) + xk0;                                         \
        if (k0 < 2000) {                                                      \
            px0a = *(const floatx4*)(xb + (size_t)xr0 * 2000 + k0);           \
            px0b = *(const floatx4*)(xb + (size_t)xr0 * 2000 + k0 + 4);       \
            px1a = *(const floatx4*)(xb + (size_t)xr1 * 2000 + k0);           \
            px1b = *(const floatx4*)(xb + (size_t)xr1 * 2000 + k0 + 4);       \
        } else { px0a = zero4; px0b = zero4; px1a = zero4; px1b = zero4; }    \
        if (t < 256) {                                                        \
            const int kw = (kbase) + wk;                                      \
            if (kw < 2000) {                                                  \
                pwa = *(const floatx4*)(Wb + (size_t)wr * 2000 + kw);         \
                pwb = *(const floatx4*)(Wb + (size_t)wr * 2000 + kw + 4);     \
            } else { pwa = zero4; pwb = zero4; }                              \
        }                                                                     \
    }

    LOAD_CHUNK(0);

    floatx4 acc0 = zero4, acc1 = zero4;
    for (int c = 0; c < 16; ++c) {
        unsigned short* xsb = (c & 1) ? xs1 : xs0;
        unsigned short* wwb = (c & 1) ? ww1 : ww0;
        // store staged chunk (coalesced 16B LDS writes, 2-way banks = free)
        *(shortx8*)&xsb[xr0 * XSTR + xk0] = pack8(px0a, px0b);
        *(shortx8*)&xsb[xr1 * XSTR + xk1] = pack8(px1a, px1b);
        if (t < 256) *(shortx8*)&wwb[wr * XSTR + wk] = pack8(pwa, pwb);
        __syncthreads();
        if (c < 15) LOAD_CHUNK((c + 1) * 128);
        // 2 MFMA per wave: K window kh*64 + {0,32} + q*8
        const unsigned short* xrow = &xsb[(rt * 16 + m) * XSTR + kh * 64 + q * 8];
        const unsigned short* wrow = &wwb[m * XSTR + kh * 64 + q * 8];
        const shortx8 a0 = *(const shortx8*)xrow;
        const shortx8 b0 = *(const shortx8*)wrow;
        const shortx8 a1 = *(const shortx8*)(xrow + 32);
        const shortx8 b1 = *(const shortx8*)(wrow + 32);
        acc0 = __builtin_amdgcn_mfma_f32_16x16x32_bf16(a0, b0, acc0, 0, 0, 0);
        acc1 = __builtin_amdgcn_mfma_f32_16x16x32_bf16(a1, b1, acc1, 0, 0, 0);
        __syncthreads();
    }
    acc0 += acc1;

    // ================= epilogue: kh-reduce + apply M + bias =================
    // C/D layout: row = q*4+v, col = m. zs[64][17]: padded, near-conflict-free.
    if (kh == 0) {
#pragma unroll
        for (int v = 0; v < 4; ++v) zs[rt * 16 + q * 4 + v][m] = acc0[v];
    }
    __syncthreads();
    if (kh == 1) {
#pragma unroll
        for (int v = 0; v < 4; ++v) zs[rt * 16 + q * 4 + v][m] += acc0[v];
    }
    __syncthreads();
    {
        const int n0 = t >> 4;        // 0..31
        const int h  = t & 15;
        const float bv = bias[ht * 16 + h];
        float s0 = bv, s1 = bv;
#pragma unroll
        for (int mm = 0; mm < 64; ++mm) {
            const float zv = zs[mm][h];                 // 16-lane broadcast
            s0 += Ms[mm * 64 + n0]      * zv;           // 4 banks x broadcast
            s1 += Ms[mm * 64 + n0 + 32] * zv;
        }
        float* yp = y + (size_t)b * 8192 + ht * 16 + h;
        yp[(size_t)n0 * 128]        = s0;
        yp[(size_t)(n0 + 32) * 128] = s1;
    }
}

extern "C" void kernel_launch(void* const* d_in, const int* in_sizes, int n_in,
                              void* d_out, int out_size, void* d_ws, size_t ws_size,
                              hipStream_t stream) {
    const float* x    = (const float*)d_in[0];   // (2048, 2000) fp32
    const int*   ei   = (const int*)d_in[1];     // (2, 4096)
    const float* ew   = (const float*)d_in[2];   // (4096,)
    const float* W    = (const float*)d_in[3];   // (128, 2000) fp32
    const float* bias = (const float*)d_in[4];   // (128,)
    float* y = (float*)d_out;                    // (32, 64, 128) fp32

    fused_all<<<256, 512, 0, stream>>>(x, W, ei, ew, bias, y);
}

// Round 8
// 97.906 us; speedup vs baseline: 2.1717x; 1.0469x over previous
//
#include <hip/hip_runtime.h>
#include <hip/hip_bf16.h>

#define EPSW 1e-6f

typedef __attribute__((ext_vector_type(4))) float floatx4;
typedef __attribute__((ext_vector_type(8))) short shortx8;   // 8 bf16 (4 VGPRs)

// round-to-nearest-even float -> bf16 bits (finite inputs)
__device__ __forceinline__ unsigned short f2bf(float f) {
    unsigned int u = __float_as_uint(f);
    u = (u + 0x7fffu + ((u >> 16) & 1u)) >> 16;
    return (unsigned short)u;
}

// pack 8 fp32 -> 8 bf16 (round-half-up: +0x8000, hi16 via v_perm).
// <=0.5 ulp vs RNE; absmax-validated rounds 3/5/7.
__device__ __forceinline__ shortx8 pack8(floatx4 a, floatx4 b) {
    union { shortx8 v; unsigned int u[4]; } r;
    const unsigned a0 = __float_as_uint(a.x) + 0x8000u, a1 = __float_as_uint(a.y) + 0x8000u;
    const unsigned a2 = __float_as_uint(a.z) + 0x8000u, a3 = __float_as_uint(a.w) + 0x8000u;
    const unsigned b0 = __float_as_uint(b.x) + 0x8000u, b1 = __float_as_uint(b.y) + 0x8000u;
    const unsigned b2 = __float_as_uint(b.z) + 0x8000u, b3 = __float_as_uint(b.w) + 0x8000u;
    r.u[0] = __builtin_amdgcn_perm(a1, a0, 0x07060302u);
    r.u[1] = __builtin_amdgcn_perm(a3, a2, 0x07060302u);
    r.u[2] = __builtin_amdgcn_perm(b1, b0, 0x07060302u);
    r.u[3] = __builtin_amdgcn_perm(b3, b2, 0x07060302u);
    return r.v;
}

// ---------------------------------------------------------------------------
// prep: 32 blocks x 256 threads (~2 us).
//   blocks 0..15 : wt transform. W (128 x 2000 fp32) -> wt bf16 in MFMA
//                  B-fragment layout [kg][h][8], kg = k/8, K padded to 2048
//                  (granules with k>=2000 zeroed). 2048 granules per block.
//   blocks 16..31: each redundantly builds A (normalized adjacency, LDS,
//                  4096 edge-ops — VALU-cheap) then one 4-column slice of
//                  Mt[c][n] = (A@A)[n][c].
// ---------------------------------------------------------------------------
__global__ __launch_bounds__(256) void prep(const float* __restrict__ W,
                                            const int* __restrict__ ei,
                                            const float* __restrict__ ew,
                                            unsigned short* __restrict__ wt,
                                            float* __restrict__ Mt) {
    const int bid = blockIdx.x;
    const int t   = threadIdx.x;
    if (bid < 16) {
#pragma unroll
        for (int i = 0; i < 8; ++i) {
            const int G  = bid * 2048 + i * 256 + t;  // 0..32767
            const int kg = G >> 7;
            const int h  = G & 127;
            const int k  = kg * 8;
            floatx4 v0 = (floatx4){0.f, 0.f, 0.f, 0.f};
            floatx4 v1 = (floatx4){0.f, 0.f, 0.f, 0.f};
            if (k < 2000) {  // kg<=249 -> whole granule valid
                v0 = *(const floatx4*)(W + (size_t)h * 2000 + k);
                v1 = *(const floatx4*)(W + (size_t)h * 2000 + k + 4);
            }
            unsigned short* p = wt + ((size_t)kg * 128 + h) * 8;
            p[0] = f2bf(v0.x); p[1] = f2bf(v0.y); p[2] = f2bf(v0.z); p[3] = f2bf(v0.w);
            p[4] = f2bf(v1.x); p[5] = f2bf(v1.y); p[6] = f2bf(v1.z); p[7] = f2bf(v1.w);
        }
    } else {
        __shared__ float A[4096];
        __shared__ float deg[64];
        __shared__ float dinv[64];
        if (t < 64) deg[t] = 1.0f;             // self-loop pre-added
        for (int i = t; i < 4096; i += 256) A[i] = 0.0f;
        __syncthreads();
        const int* srcp = ei;
        const int* dstp = ei + 4096;
#pragma unroll
        for (int i = 0; i < 16; ++i) {
            const int e = i * 256 + t;
            float w = ew[e];
            w = (w <= 0.0f) ? EPSW : w;
            atomicAdd(&deg[dstp[e]], w);
        }
        __syncthreads();
        if (t < 64) dinv[t] = 1.0f / sqrtf(deg[t]);
        __syncthreads();
#pragma unroll
        for (int i = 0; i < 16; ++i) {
            const int e = i * 256 + t;
            float w = ew[e];
            w = (w <= 0.0f) ? EPSW : w;
            const int s = srcp[e], d = dstp[e];
            atomicAdd(&A[d * 64 + s], dinv[s] * w * dinv[d]);
        }
        if (t < 64) atomicAdd(&A[t * 64 + t], dinv[t] * dinv[t]);
        __syncthreads();
        // Mt[c][n] = (A@A)[n][c], 4 columns per block, 1 output/thread
        const int c = (bid - 16) * 4 + (t >> 6);
        const int n = t & 63;
        float s = 0.0f;
#pragma unroll 8
        for (int k = 0; k < 64; ++k) s += A[n * 64 + k] * A[k * 64 + c];
        Mt[c * 64 + n] = s;
    }
}

// ---------------------------------------------------------------------------
// gemm_apply: 256 blocks x 512 threads. Block bid = ht*32 + b (bid%8 == b%8
// -> XCD round-robin pins 4 batches/XCD; 8x x re-reads hit that XCD's L2).
// Main loop: NO LDS, NO barriers. Wave (rt, kh) owns a 16x16 tile (rows
// rt*16.., h ht*16..) over K-half kh*1024. Per k-step (32 k): a-frag = 2
// coalesced float4 loads straight from fp32 x + inline pack8 (the f0/f1
// pair fully consumes each 128B line); b-frag = one 16B load from pre-baked
// wt (L2-resident). 32 steps, unroll 8 -> ~24 loads in flight per wave,
// 8 waves/CU.
// Epilogue: Ms staged from global Mt (loads issued at kernel start),
// kh-halves reduced via zs[64][17] (round-5-validated), y = M.z + bias.
// ---------------------------------------------------------------------------
__global__ __launch_bounds__(512) void gemm_apply(
        const float* __restrict__ x,
        const unsigned short* __restrict__ wt,
        const float* __restrict__ Mt,
        const float* __restrict__ bias,
        float* __restrict__ y) {
    __shared__ float Ms[4096];        // Ms[m*64+n] = M[n][m]
    __shared__ float zs[64][17];
    const int t    = threadIdx.x;
    const int bid  = blockIdx.x;
    const int b    = bid & 31;
    const int ht   = bid >> 5;
    const int wave = t >> 6, lane = t & 63;
    const int m = lane & 15, q = lane >> 4;
    const int rt = wave & 3, kh = wave >> 2;

    // stage Ms: global loads issued before the MFMA loop (latency hidden)
    {
        const floatx4* Mg4 = (const floatx4*)Mt;
        floatx4* Ms4 = (floatx4*)Ms;
        Ms4[t]       = Mg4[t];
        Ms4[t + 512] = Mg4[t + 512];
    }

    const float* xrow = x + (size_t)(b * 64 + rt * 16 + m) * 2000;
    const int kbase = kh * 1024 + q * 8;
    const shortx8* Bg = (const shortx8*)wt;
    const int gb = (kh * 128 + q) * 128 + ht * 16 + m;   // +512 per step

    const floatx4 zero4 = (floatx4){0.f, 0.f, 0.f, 0.f};
    floatx4 acc0 = zero4, acc1 = zero4;
#pragma unroll 8
    for (int s = 0; s < 32; ++s) {
        const int k0 = kbase + s * 32;
        floatx4 f0 = zero4, f1 = zero4;
        if (k0 < 2000) {               // k0 % 8 == 0, so k0 < 2000 => k0+8 <= 2000
            f0 = *(const floatx4*)(xrow + k0);
            f1 = *(const floatx4*)(xrow + k0 + 4);
        }
        const shortx8 af = pack8(f0, f1);
        const shortx8 bf = Bg[gb + s * 512];
        if (s & 1) acc1 = __builtin_amdgcn_mfma_f32_16x16x32_bf16(af, bf, acc1, 0, 0, 0);
        else       acc0 = __builtin_amdgcn_mfma_f32_16x16x32_bf16(af, bf, acc0, 0, 0, 0);
    }
    acc0 += acc1;

    // ===== kh-reduce + apply M + bias (round-5-validated) =====
    // C/D layout: row = q*4+v, col = m. zs padded [64][17]: <=2-way banks.
    if (kh == 0) {
#pragma unroll
        for (int v = 0; v < 4; ++v) zs[rt * 16 + q * 4 + v][m] = acc0[v];
    }
    __syncthreads();
    if (kh == 1) {
#pragma unroll
        for (int v = 0; v < 4; ++v) zs[rt * 16 + q * 4 + v][m] += acc0[v];
    }
    __syncthreads();
    {
        const int n0 = t >> 4;        // 0..31
        const int h  = t & 15;
        const float bv = bias[ht * 16 + h];
        float s0 = bv, s1 = bv;
#pragma unroll
        for (int mm = 0; mm < 64; ++mm) {
            const float zv = zs[mm][h];                 // 16-lane broadcast
            s0 += Ms[mm * 64 + n0]      * zv;           // 4 banks x broadcast
            s1 += Ms[mm * 64 + n0 + 32] * zv;
        }
        float* yp = y + (size_t)b * 8192 + ht * 16 + h;
        yp[(size_t)n0 * 128]        = s0;
        yp[(size_t)(n0 + 32) * 128] = s1;
    }
}

extern "C" void kernel_launch(void* const* d_in, const int* in_sizes, int n_in,
                              void* d_out, int out_size, void* d_ws, size_t ws_size,
                              hipStream_t stream) {
    const float* x    = (const float*)d_in[0];   // (2048, 2000) fp32
    const int*   ei   = (const int*)d_in[1];     // (2, 4096)
    const float* ew   = (const float*)d_in[2];   // (4096,)
    const float* W    = (const float*)d_in[3];   // (128, 2000) fp32
    const float* bias = (const float*)d_in[4];   // (128,)
    float* y = (float*)d_out;                    // (32, 64, 128) fp32

    float* Mt = (float*)d_ws;                            // 4096 f
    unsigned short* wt = (unsigned short*)(Mt + 4096);   // 256*128*8 bf16 (512 KB)

    prep<<<32, 256, 0, stream>>>(W, ei, ew, wt, Mt);
    gemm_apply<<<256, 512, 0, stream>>>(x, wt, Mt, bias, y);
}